// Round 11
// baseline (483.818 us; speedup 1.0000x reference)
//
#include <hip/hip_runtime.h>
#include <hip/hip_fp16.h>
#include <math.h>

#define N_NODES 50000
#define N_EDGES 800000
#define DIM 64
#define N_LAYERS 5

#define BLK 256      // four waves: 8 gather-rows per wave (R10-proven layout)
#define ROWS 32      // rows per chunk
#define HSTRIDE 68   // 16B-aligned rows, bank-spread
#define POOL_REP 64  // pool atomic chain depth 1563/64 ~ 24

#define CAP 64       // ELL row capacity (deg ~ Poisson(16); P(>64) ~ 1e-13, guarded)
#define NB 196       // buckets of 256 dst rows
#define NROW_PAD (NB * 256)   // 50176
#define CAPB 5632    // per-bucket edge capacity (mean 4082, sigma ~64)
#define BF_BLOCKS 512
#define EPB2 ((N_EDGES + BF_BLOCKS - 1) / BF_BLOCKS)   // 1563 edges per fill chunk

#define GRID_C 784   // fused-layer grid; 4 blocks/CU guaranteed by __launch_bounds__(256,4)
#define NCHUNK 1563  // 32-row chunks covering 50016 rows

#define WFRAG_PER_LAYER (3 * 2 * 4 * 64 * 8)   // 12288 shorts (hi-only)
#define XP (N_NODES * DIM / 4)                  // 800000 x-conv items
#define WP (N_LAYERS * WFRAG_PER_LAYER)         // 61440 w-conv items
#define PREP_BLOCKS ((XP + WP) / 256)           // 3365 exact

typedef __attribute__((ext_vector_type(8))) short short8;
typedef __attribute__((ext_vector_type(8))) unsigned short ushort8_t;
typedef __attribute__((ext_vector_type(4))) float floatx4;

__device__ inline unsigned short bf16_rne(float f) {
    unsigned int u = __float_as_uint(f);
    return (unsigned short)((u + 0x7FFFu + ((u >> 16) & 1u)) >> 16);
}
__device__ inline float e5m2_f32(unsigned char b) {
    return __half2float(__ushort_as_half((unsigned short)((unsigned short)b << 8)));
}
__device__ inline unsigned char f32_e5m2(float f) {
    unsigned short us = __half_as_ushort(__float2half(f));
    us = (unsigned short)(us + 0x7F + ((us >> 8) & 1));
    return (unsigned char)(us >> 8);
}
__device__ inline __half2 e5m2x2_lo(unsigned d) {
    unsigned h = __builtin_amdgcn_perm(0u, d, 0x01050004u);
    return __builtin_bit_cast(__half2, h);
}
__device__ inline __half2 e5m2x2_hi(unsigned d) {
    unsigned h = __builtin_amdgcn_perm(0u, d, 0x03070206u);
    return __builtin_bit_cast(__half2, h);
}

// ---------------- merged setup (R6-proven): prep + bucketed edge partition ----------------
__global__ __launch_bounds__(256) void setup_kernel(const float* __restrict__ x,
                                                    const float* __restrict__ W,
                                                    const int* __restrict__ src,
                                                    const int* __restrict__ dst,
                                                    unsigned char* __restrict__ x8,
                                                    unsigned short* __restrict__ wfrag,
                                                    int* __restrict__ bucketCnt,
                                                    int* __restrict__ ebuf) {
    __shared__ int cnt[NB];
    __shared__ int basev[NB];
    int b = blockIdx.x;
    const int t = threadIdx.x;
    if (b < PREP_BLOCKS) {
        int i = b * 256 + t;
        if (i < XP) {
            float4 v = ((const float4*)x)[i];
            uchar4 u;
            u.x = f32_e5m2(v.x); u.y = f32_e5m2(v.y);
            u.z = f32_e5m2(v.z); u.w = f32_e5m2(v.w);
            ((uchar4*)x8)[i] = u;
        } else {
            int tt = i - XP;
            int j    = tt & 7;
            int lane = (tt >> 3) & 63;
            int nt   = (tt >> 9) & 3;
            int kt   = (tt >> 11) & 1;
            int rest = tt >> 12;
            int p    = rest % 3;
            int layer= rest / 3;
            int k = kt * 32 + (lane >> 4) * 8 + j;
            int n = nt * 16 + (lane & 15);
            float v = W[(((size_t)layer * 3 + p) * 64 + k) * 64 + n];
            wfrag[tt] = bf16_rne(v);
        }
        return;
    }
    b -= PREP_BLOCKS;
    const int e0 = b * EPB2;
    for (int j = t; j < NB; j += 256) cnt[j] = 0;
    __syncthreads();
    for (int i = t; i < EPB2; i += 256) {
        int e = e0 + i;
        if (e < N_EDGES) atomicAdd(&cnt[dst[e] >> 8], 1);
    }
    __syncthreads();
    for (int j = t; j < NB; j += 256) {
        int c = cnt[j];
        basev[j] = c ? atomicAdd(&bucketCnt[j], c) : 0;
        cnt[j] = 0;
    }
    __syncthreads();
    for (int i = t; i < EPB2; i += 256) {
        int e = e0 + i;
        if (e < N_EDGES) {
            int d = dst[e];
            int bb = d >> 8;
            int pos = atomicAdd(&cnt[bb], 1);
            ebuf[(size_t)bb * CAPB + basev[bb] + pos] = ((d & 255) << 16) | src[e];
        }
    }
}

// ---------------- bucket -> ELL: LDS scatter tile, coalesced uint4 writeout ----------------
__global__ __launch_bounds__(512) void bell_kernel(const int* __restrict__ ebuf,
                                                   const int* __restrict__ bucketCnt,
                                                   int* __restrict__ rowCnt,
                                                   unsigned short* __restrict__ ell) {
    __shared__ int cur[256];
    __shared__ unsigned short tile[256 * CAP];   // 32 KB
    const int t = threadIdx.x;
    const int b = blockIdx.x;
    const int cnt_b = min(bucketCnt[b], CAPB);
    const int* __restrict__ ereg = ebuf + (size_t)b * CAPB;

    if (t < 256) cur[t] = 0;
    __syncthreads();
    for (int i = t; i < cnt_b; i += 512) {
        int e = ereg[i];
        int r = (e >> 16) & 255;
        int pos = atomicAdd(&cur[r], 1);
        if (pos < CAP)
            tile[r * CAP + pos] = (unsigned short)(e & 0xFFFF);
    }
    __syncthreads();
    if (t < 256) rowCnt[b * 256 + t] = min(cur[t], CAP);
    uint4* eo = (uint4*)(ell + (size_t)b * 256 * CAP);
    const uint4* ti = (const uint4*)tile;
    #pragma unroll
    for (int j = 0; j < 4; ++j)
        eo[t + j * 512] = ti[t + j * 512];
}

// ---------------- one 32-row layer chunk (R10-proven 4-wave body) ----------------
__device__ __forceinline__ void layer_chunk(const int v,
                                            const unsigned char* __restrict__ h8,
                                            const int* __restrict__ rowCnt,
                                            const unsigned short* __restrict__ ell,
                                            const unsigned short* __restrict__ wf,
                                            unsigned char* __restrict__ h_out,
                                            float* __restrict__ pooled,
                                            float* H) {
    const int tid  = threadIdx.x;
    const int lane = tid & 63;
    const int w    = __builtin_amdgcn_readfirstlane(tid >> 6);   // 0..3
    const int n0   = v * ROWS;
    const int nw8  = n0 + w * 8;
    const int o8   = (lane & 7) << 3;
    const int rg   = lane >> 3;

    {
        const int cv = rowCnt[nw8 + (lane & 7)];
        const int deg = min(__shfl(cv, rg, 64), CAP);
        int Rm = deg;
        Rm = max(Rm, __shfl_xor(Rm, 8, 64));
        Rm = max(Rm, __shfl_xor(Rm, 16, 64));
        Rm = max(Rm, __shfl_xor(Rm, 32, 64));
        const int Rpad = (Rm + 7) & ~7;
        const int rowq = nw8 + rg;
        const int rq6  = rowq << 6;
        const unsigned short* ep = ell + ((size_t)rowq << 6);

        __half2 a01 = __float2half2_rn(0.f);
        __half2 a23 = a01, a45 = a01, a67 = a01;

        for (int i = 0; i < Rpad; i += 8) {
            ushort8_t ev = *(const ushort8_t*)(ep + i);
            uint2 dv[8];
            #pragma unroll
            for (int k = 0; k < 8; ++k) {
                int s6 = ((int)ev[k]) << 6;
                s6 = (i + k < deg) ? s6 : rq6;
                dv[k] = *(const uint2*)(h8 + (unsigned)(s6 | o8));
            }
            #pragma unroll
            for (int k = 0; k < 8; ++k) {
                a01 = __hadd2(a01, e5m2x2_lo(dv[k].x));
                a23 = __hadd2(a23, e5m2x2_hi(dv[k].x));
                a45 = __hadd2(a45, e5m2x2_lo(dv[k].y));
                a67 = __hadd2(a67, e5m2x2_hi(dv[k].y));
            }
        }

        uint2 sd = *(const uint2*)(h8 + (unsigned)(rq6 | o8));
        float scale = (float)(1 - (Rpad - deg));
        float2 f01 = __half22float2(a01), f23 = __half22float2(a23);
        float2 f45 = __half22float2(a45), f67 = __half22float2(a67);
        float4 r0, r1;
        r0.x = f01.x + e5m2_f32((unsigned char)(sd.x      )) * scale;
        r0.y = f01.y + e5m2_f32((unsigned char)(sd.x >>  8)) * scale;
        r0.z = f23.x + e5m2_f32((unsigned char)(sd.x >> 16)) * scale;
        r0.w = f23.y + e5m2_f32((unsigned char)(sd.x >> 24)) * scale;
        r1.x = f45.x + e5m2_f32((unsigned char)(sd.y      )) * scale;
        r1.y = f45.y + e5m2_f32((unsigned char)(sd.y >>  8)) * scale;
        r1.z = f67.x + e5m2_f32((unsigned char)(sd.y >> 16)) * scale;
        r1.w = f67.y + e5m2_f32((unsigned char)(sd.y >> 24)) * scale;
        if (rowq >= N_NODES) {
            r0.x = 0.f; r0.y = 0.f; r0.z = 0.f; r0.w = 0.f;
            r1.x = 0.f; r1.y = 0.f; r1.z = 0.f; r1.w = 0.f;
        }
        float* hp = &H[(w * 8 + rg) * HSTRIDE + o8];
        *(float4*)hp = r0;
        *(float4*)(hp + 4) = r1;
    }
    __syncthreads();

    if (w < 2) {
        const int mrow = lane & 15;
        const int quad = lane >> 4;
        const short8* Bf = (const short8*)wf;

        for (int p = 0; p < 3; ++p) {
            short8 Ahi[2];
            #pragma unroll
            for (int kt = 0; kt < 2; ++kt) {
                const float* ap = &H[(w * 16 + mrow) * HSTRIDE + kt * 32 + quad * 8];
                float4 f0 = *(const float4*)ap;
                float4 f1 = *(const float4*)(ap + 4);
                float fv[8] = {f0.x, f0.y, f0.z, f0.w, f1.x, f1.y, f1.z, f1.w};
                short8 hi;
                #pragma unroll
                for (int jj = 0; jj < 8; ++jj)
                    hi[jj] = (short)bf16_rne(fv[jj]);
                Ahi[kt] = hi;
            }
            floatx4 acc[4];
            #pragma unroll
            for (int nt = 0; nt < 4; ++nt) { acc[nt][0]=0.f; acc[nt][1]=0.f; acc[nt][2]=0.f; acc[nt][3]=0.f; }
            #pragma unroll
            for (int nt = 0; nt < 4; ++nt) {
                #pragma unroll
                for (int kt = 0; kt < 2; ++kt) {
                    int fbase = ((p * 2 + kt) * 4 + nt) * 64 + lane;
                    short8 bhi = Bf[fbase];
                    acc[nt] = __builtin_amdgcn_mfma_f32_16x16x32_bf16(Ahi[kt], bhi, acc[nt], 0, 0, 0);
                }
            }
            #pragma unroll
            for (int nt = 0; nt < 4; ++nt) {
                #pragma unroll
                for (int reg = 0; reg < 4; ++reg) {
                    int row = w * 16 + quad * 4 + reg;
                    H[row * HSTRIDE + nt * 16 + mrow] = fmaxf(acc[nt][reg], 0.f);
                }
            }
        }
    }
    __syncthreads();

    #pragma unroll
    for (int i = 0; i < 2; ++i) {
        int t4 = tid + i * BLK;
        int r  = t4 >> 4;
        int c  = (t4 & 15) << 2;
        int grow = n0 + r;
        if (grow < N_NODES) {
            float4 vv = *(const float4*)&H[r * HSTRIDE + c];
            uchar4 u;
            u.x = f32_e5m2(vv.x); u.y = f32_e5m2(vv.y);
            u.z = f32_e5m2(vv.z); u.w = f32_e5m2(vv.w);
            *(uchar4*)(h_out + (size_t)grow * DIM + c) = u;
        }
    }
    if (tid < 64) {
        float s = 0.f;
        #pragma unroll
        for (int r = 0; r < ROWS; ++r)
            s += H[r * HSTRIDE + tid];
        atomicAdd(&pooled[(v & (POOL_REP - 1)) * DIM + tid], s);
    }
}

// ---- grid barrier v2: 4-way split arrivals (release), leader-only RELAXED spin with deep
// backoff, single acquire fence per wave AFTER exit (R5 poison = per-poll ACQUIRE invalidates).
__device__ __forceinline__ void gbar2(int* bar, int gen) {
    __syncthreads();
    if (threadIdx.x == 0) {
        const int grp = blockIdx.x & 3;
        int c = __hip_atomic_fetch_add(&bar[grp * 32], 1, __ATOMIC_RELEASE, __HIP_MEMORY_SCOPE_AGENT);
        if (c == 196 * (gen + 1) - 1) {                     // last arrival of this group
            int r = __hip_atomic_fetch_add(&bar[128], 1, __ATOMIC_ACQ_REL, __HIP_MEMORY_SCOPE_AGENT);
            if (r == 4 * (gen + 1) - 1)                     // last group -> release flag
                __hip_atomic_store(&bar[160], gen + 1, __ATOMIC_RELEASE, __HIP_MEMORY_SCOPE_AGENT);
        }
        while (__hip_atomic_load(&bar[160], __ATOMIC_RELAXED, __HIP_MEMORY_SCOPE_AGENT) < gen + 1)
            __builtin_amdgcn_s_sleep(64);
    }
    __syncthreads();
    __threadfence();   // acquire: invalidate stale L1/L2 h-buffer lines (clustered, post-barrier)
}

// ---------------- fused 5-layer + finalize (784 co-resident blocks by __launch_bounds__(256,4)) ----
__global__ __launch_bounds__(BLK, 4) void gin5_kernel(const unsigned char* __restrict__ hX,
                                                      unsigned char* __restrict__ hA,
                                                      unsigned char* __restrict__ hB,
                                                      const int* __restrict__ rowCnt,
                                                      const unsigned short* __restrict__ ell,
                                                      const unsigned short* __restrict__ wfrag,
                                                      float* __restrict__ pooled,
                                                      int* __restrict__ bar,
                                                      const float* __restrict__ Wl,
                                                      float* __restrict__ out) {
    __shared__ float H[ROWS * HSTRIDE];   // 8.7 KB
    const int b = blockIdx.x;

    for (int l = 0; l < N_LAYERS; ++l) {
        const unsigned char* hc = (l == 0) ? hX : ((l & 1) ? hA : hB);
        unsigned char* hn = (l & 1) ? hB : hA;
        const unsigned short* wf = wfrag + (size_t)l * WFRAG_PER_LAYER;
        float* pl = pooled + (size_t)l * POOL_REP * DIM;

        layer_chunk(b, hc, rowCnt, ell, wf, hn, pl, H);
        __syncthreads();                         // H reuse WAR across chunks
        if (b + GRID_C < NCHUNK)
            layer_chunk(b + GRID_C, hc, rowCnt, ell, wf, hn, pl, H);

        gbar2(bar, l);                           // cross-layer (and pre-finalize) global sync
    }

    // ---- finalize by block 0 (pooled atomics all done; caches invalidated by gbar2) ----
    if (b == 0 && threadIdx.x < 64) {
        int c = threadIdx.x;
        float s = 0.f;
        for (int l = 0; l < N_LAYERS; ++l) {
            float col = 0.f;
            for (int r = 0; r < POOL_REP; ++r)
                col += pooled[(l * POOL_REP + r) * DIM + c];
            s += col * Wl[l * DIM + c];
        }
        #pragma unroll
        for (int off = 32; off > 0; off >>= 1)
            s += __shfl_down(s, off, 64);
        if (c == 0) {
            float logit = s / (float)N_NODES;
            out[0] = 1.f / (1.f + expf(-logit));
        }
    }
}

extern "C" void kernel_launch(void* const* d_in, const int* in_sizes, int n_in,
                              void* d_out, int out_size, void* d_ws, size_t ws_size,
                              hipStream_t stream) {
    const float* x   = (const float*)d_in[0];
    const float* W   = (const float*)d_in[1];
    const float* Wl  = (const float*)d_in[2];
    const int*   src = (const int*)d_in[3];
    const int*   dst = (const int*)d_in[4];
    float* out = (float*)d_out;

    char* ws = (char*)d_ws;
    const size_t h8Bytes = (size_t)N_NODES * DIM;                     // 3.2 MB
    unsigned char* hX = (unsigned char*)(ws);
    unsigned char* hA = (unsigned char*)(ws + h8Bytes);
    unsigned char* hB = (unsigned char*)(ws + 2 * h8Bytes);
    unsigned short* ell = (unsigned short*)(ws + 3 * h8Bytes);        // 50176*64 ushort = 6.4 MB
    int*   ebuf     = (int*)(ell + (size_t)NROW_PAD * CAP);           // 4.4 MB
    int*   rowCnt   = ebuf + (size_t)NB * CAPB;                       // 50176 ints
    int*   bucketCnt= rowCnt + NROW_PAD;                              // 256 ints
    int*   bar      = bucketCnt + 256;                                // 256 ints (4 grp + root + flag)
    float* pooled   = (float*)(bar + 256);                            // 5*64*64 floats
    unsigned short* wfrag = (unsigned short*)(pooled + N_LAYERS * POOL_REP * DIM);

    // zero bucketCnt + bar + pooled in one stream-ordered memset (before any atomics)
    hipMemsetAsync(bucketCnt, 0, (256 + 256 + N_LAYERS * POOL_REP * DIM) * sizeof(int), stream);

    setup_kernel<<<PREP_BLOCKS + BF_BLOCKS, 256, 0, stream>>>(x, W, src, dst, hX, wfrag, bucketCnt, ebuf);
    bell_kernel<<<NB, 512, 0, stream>>>(ebuf, bucketCnt, rowCnt, ell);
    gin5_kernel<<<GRID_C, BLK, 0, stream>>>(hX, hA, hB, rowCnt, ell, wfrag, pooled, bar, Wl, out);
}

// Round 12
// 272.614 us; speedup vs baseline: 1.7747x; 1.7747x over previous
//
#include <hip/hip_runtime.h>
#include <hip/hip_fp16.h>
#include <math.h>

#define N_NODES 50000
#define N_EDGES 800000
#define DIM 64
#define N_LAYERS 5

#define BLK 128      // two waves per block (R9 measured-best)
#define ROWS 32      // 16 rows per wave
#define HSTRIDE 68   // 16B-aligned rows, bank-spread
#define POOL_REP 64  // pool atomic chain depth 1563/64 ~ 24 (was 98)
#define GRID_L ((N_NODES + ROWS - 1) / ROWS)   // 1563

#define CAP 64       // ELL row capacity (deg ~ Poisson(16); P(>64) ~ 1e-13, guarded)
#define NB 196       // buckets of 256 dst rows
#define NROW_PAD (NB * 256)   // 50176
#define CAPB 5632    // per-bucket edge capacity (mean 4082, sigma ~64)
#define BF_BLOCKS 512
#define EPB2 ((N_EDGES + BF_BLOCKS - 1) / BF_BLOCKS)   // 1563 edges per fill chunk

#define WFRAG_PER_LAYER (3 * 2 * 4 * 64 * 8)   // 12288 shorts (hi-only)
#define XP (N_NODES * DIM / 4)                  // 800000 x-conv items
#define WP (N_LAYERS * WFRAG_PER_LAYER)         // 61440 w-conv items
#define PREP_BLOCKS ((XP + WP) / 256)           // 3365 exact

typedef __attribute__((ext_vector_type(8))) short short8;
typedef __attribute__((ext_vector_type(8))) unsigned short ushort8_t;
typedef __attribute__((ext_vector_type(4))) float floatx4;

__device__ inline unsigned short bf16_rne(float f) {
    unsigned int u = __float_as_uint(f);
    return (unsigned short)((u + 0x7FFFu + ((u >> 16) & 1u)) >> 16);
}
// fp8 e5m2 = top byte of fp16. Decode: 2 ops. Encode: f32->f16 RNE, then RNE on 8-bit boundary.
__device__ inline float e5m2_f32(unsigned char b) {
    return __half2float(__ushort_as_half((unsigned short)((unsigned short)b << 8)));
}
__device__ inline unsigned char f32_e5m2(float f) {
    unsigned short us = __half_as_ushort(__float2half(f));
    us = (unsigned short)(us + 0x7F + ((us >> 8) & 1));
    return (unsigned char)(us >> 8);
}
// Pack bytes {b0,b1} / {b2,b3} of a dword into half2 {b<<8, b'<<8} via v_perm_b32.
__device__ inline __half2 e5m2x2_lo(unsigned d) {
    unsigned h = __builtin_amdgcn_perm(0u, d, 0x01050004u);  // bytes [0,b0,0,b1]
    return __builtin_bit_cast(__half2, h);
}
__device__ inline __half2 e5m2x2_hi(unsigned d) {
    unsigned h = __builtin_amdgcn_perm(0u, d, 0x03070206u);  // bytes [0,b2,0,b3]
    return __builtin_bit_cast(__half2, h);
}

// ---------------- merged setup (R6-proven): prep (x->fp8, W->frags) + bucketed edge partition ----
// bucketCnt zeroed by hipMemsetAsync BEFORE this kernel (stream-ordered).
__global__ __launch_bounds__(256) void setup_kernel(const float* __restrict__ x,
                                                    const float* __restrict__ W,
                                                    const int* __restrict__ src,
                                                    const int* __restrict__ dst,
                                                    unsigned char* __restrict__ x8,
                                                    unsigned short* __restrict__ wfrag,
                                                    int* __restrict__ bucketCnt,
                                                    int* __restrict__ ebuf) {
    __shared__ int cnt[NB];
    __shared__ int basev[NB];
    int b = blockIdx.x;
    const int t = threadIdx.x;
    if (b < PREP_BLOCKS) {
        int i = b * 256 + t;
        if (i < XP) {
            float4 v = ((const float4*)x)[i];
            uchar4 u;
            u.x = f32_e5m2(v.x); u.y = f32_e5m2(v.y);
            u.z = f32_e5m2(v.z); u.w = f32_e5m2(v.w);
            ((uchar4*)x8)[i] = u;
        } else {
            int tt = i - XP;   // < WP exactly
            int j    = tt & 7;
            int lane = (tt >> 3) & 63;
            int nt   = (tt >> 9) & 3;
            int kt   = (tt >> 11) & 1;
            int rest = tt >> 12;
            int p    = rest % 3;
            int layer= rest / 3;
            int k = kt * 32 + (lane >> 4) * 8 + j;
            int n = nt * 16 + (lane & 15);
            float v = W[(((size_t)layer * 3 + p) * 64 + k) * 64 + n];
            wfrag[tt] = bf16_rne(v);
        }
        return;
    }
    // ---- bfill part: bucketed partition of one edge chunk (LDS atomics only) ----
    b -= PREP_BLOCKS;
    const int e0 = b * EPB2;
    for (int j = t; j < NB; j += 256) cnt[j] = 0;
    __syncthreads();
    for (int i = t; i < EPB2; i += 256) {
        int e = e0 + i;
        if (e < N_EDGES) atomicAdd(&cnt[dst[e] >> 8], 1);
    }
    __syncthreads();
    for (int j = t; j < NB; j += 256) {
        int c = cnt[j];
        basev[j] = c ? atomicAdd(&bucketCnt[j], c) : 0;
        cnt[j] = 0;   // reuse as in-block cursor
    }
    __syncthreads();
    for (int i = t; i < EPB2; i += 256) {
        int e = e0 + i;
        if (e < N_EDGES) {
            int d = dst[e];
            int bb = d >> 8;
            int pos = atomicAdd(&cnt[bb], 1);
            ebuf[(size_t)bb * CAPB + basev[bb] + pos] = ((d & 255) << 16) | src[e];
        }
    }
}

// ---------------- bucket -> ELL: LDS scatter tile, coalesced uint4 writeout ----------------
__global__ __launch_bounds__(512) void bell_kernel(const int* __restrict__ ebuf,
                                                   const int* __restrict__ bucketCnt,
                                                   int* __restrict__ rowCnt,
                                                   unsigned short* __restrict__ ell) {
    __shared__ int cur[256];
    __shared__ unsigned short tile[256 * CAP];   // 32 KB
    const int t = threadIdx.x;       // 0..511
    const int b = blockIdx.x;
    const int cnt_b = min(bucketCnt[b], CAPB);
    const int* __restrict__ ereg = ebuf + (size_t)b * CAPB;

    if (t < 256) cur[t] = 0;
    __syncthreads();
    for (int i = t; i < cnt_b; i += 512) {
        int e = ereg[i];
        int r = (e >> 16) & 255;
        int pos = atomicAdd(&cur[r], 1);
        if (pos < CAP)                        // overflow guard: degrade, don't corrupt
            tile[r * CAP + pos] = (unsigned short)(e & 0xFFFF);
    }
    __syncthreads();
    if (t < 256) rowCnt[b * 256 + t] = min(cur[t], CAP);
    // coalesced writeout: 2048 uint4 per bucket (pad slots carry garbage; consumer masks by deg)
    uint4* eo = (uint4*)(ell + (size_t)b * 256 * CAP);
    const uint4* ti = (const uint4*)tile;
    #pragma unroll
    for (int j = 0; j < 4; ++j)
        eo[t + j * 512] = ti[t + j * 512];
}

// ---------------- fused layer (R9 ELL gather, measured-best) + last-block finalize ----------------
__global__ __launch_bounds__(BLK) void layer_kernel(const unsigned char* __restrict__ h8,
                                                    const int* __restrict__ rowCnt,
                                                    const unsigned short* __restrict__ ell,
                                                    const unsigned short* __restrict__ wf,
                                                    unsigned char* __restrict__ h_out,
                                                    float* __restrict__ pooled,   // this layer's [POOL_REP][64]
                                                    int doFinal,
                                                    int* __restrict__ ticket,
                                                    const float* __restrict__ poolAll,  // [L][POOL_REP][64]
                                                    const float* __restrict__ Wl,
                                                    float* __restrict__ out) {
    __shared__ float H[ROWS * HSTRIDE];   // 8.7 KB
    __shared__ int winner;
    const int tid  = threadIdx.x;
    const int lane = tid & 63;
    const int w    = __builtin_amdgcn_readfirstlane(tid >> 6);
    const int n0   = blockIdx.x * ROWS;
    const int nw   = n0 + w * 16;
    const int o8   = (lane & 7) << 3;     // byte offset of this lane's 8 dims
    const int rg   = lane >> 3;           // row id 0..7 within octet-group

    const int cv = rowCnt[nw + (lane & 15)];   // per-row degree (16 rows, broadcast x4)

    // 2 groups of 8 rows; octet rg owns row 8g+rg; lane holds 8 dims at byte offset o8
    for (int g = 0; g < 2; ++g) {
        const int myrow = g * 8 + rg;
        const int deg = min(__shfl(cv, myrow, 64), CAP);
        int Rm = deg;
        Rm = max(Rm, __shfl_xor(Rm, 8, 64));
        Rm = max(Rm, __shfl_xor(Rm, 16, 64));
        Rm = max(Rm, __shfl_xor(Rm, 32, 64));   // max over the 8 rows -> wave-uniform
        const int Rpad = (Rm + 7) & ~7;
        const int rowq = nw + myrow;
        const int rq6  = rowq << 6;
        const unsigned short* ep = ell + ((size_t)rowq << 6);  // CAP=64 stride

        __half2 a01 = __float2half2_rn(0.f);
        __half2 a23 = a01, a45 = a01, a67 = a01;

        for (int i = 0; i < Rpad; i += 8) {
            ushort8_t ev = *(const ushort8_t*)(ep + i);   // 8 edge ids, broadcast across 8 lanes
            uint2 dv[8];
            #pragma unroll
            for (int k = 0; k < 8; ++k) {
                int s6 = ((int)ev[k]) << 6;
                s6 = (i + k < deg) ? s6 : rq6;            // pad slots -> self (cancelled below)
                dv[k] = *(const uint2*)(h8 + (unsigned)(s6 | o8));
            }
            #pragma unroll
            for (int k = 0; k < 8; ++k) {
                a01 = __hadd2(a01, e5m2x2_lo(dv[k].x));
                a23 = __hadd2(a23, e5m2x2_hi(dv[k].x));
                a45 = __hadd2(a45, e5m2x2_lo(dv[k].y));
                a67 = __hadd2(a67, e5m2x2_hi(dv[k].y));
            }
        }

        // self + exact pad-cancellation (pads added self Rpad-deg times)
        uint2 sd = *(const uint2*)(h8 + (unsigned)(rq6 | o8));
        float scale = (float)(1 - (Rpad - deg));
        float2 f01 = __half22float2(a01), f23 = __half22float2(a23);
        float2 f45 = __half22float2(a45), f67 = __half22float2(a67);
        float4 r0, r1;
        r0.x = f01.x + e5m2_f32((unsigned char)(sd.x      )) * scale;
        r0.y = f01.y + e5m2_f32((unsigned char)(sd.x >>  8)) * scale;
        r0.z = f23.x + e5m2_f32((unsigned char)(sd.x >> 16)) * scale;
        r0.w = f23.y + e5m2_f32((unsigned char)(sd.x >> 24)) * scale;
        r1.x = f45.x + e5m2_f32((unsigned char)(sd.y      )) * scale;
        r1.y = f45.y + e5m2_f32((unsigned char)(sd.y >>  8)) * scale;
        r1.z = f67.x + e5m2_f32((unsigned char)(sd.y >> 16)) * scale;
        r1.w = f67.y + e5m2_f32((unsigned char)(sd.y >> 24)) * scale;
        if (rowq >= N_NODES) {
            r0.x = 0.f; r0.y = 0.f; r0.z = 0.f; r0.w = 0.f;
            r1.x = 0.f; r1.y = 0.f; r1.z = 0.f; r1.w = 0.f;
        }
        float* hp = &H[(w * 16 + myrow) * HSTRIDE + o8];
        *(float4*)hp = r0;
        *(float4*)(hp + 4) = r1;
    }
    // no __syncthreads: aggregation, MFMA A/outputs, relu writes all stay within
    // this wave's 16 H rows; per-wave DS-pipe ordering guarantees RAW/WAR.
    asm volatile("s_waitcnt lgkmcnt(0)" ::: "memory");

    // ---- MLP: hi-only bf16 MFMA (wave-private in H; zero inter-stage barriers) ----
    const int mrow = lane & 15;
    const int quad = lane >> 4;
    const short8* Bf = (const short8*)wf;

    for (int p = 0; p < 3; ++p) {
        short8 Ahi[2];
        #pragma unroll
        for (int kt = 0; kt < 2; ++kt) {
            const float* ap = &H[(w * 16 + mrow) * HSTRIDE + kt * 32 + quad * 8];
            float4 f0 = *(const float4*)ap;
            float4 f1 = *(const float4*)(ap + 4);
            float fv[8] = {f0.x, f0.y, f0.z, f0.w, f1.x, f1.y, f1.z, f1.w};
            short8 hi;
            #pragma unroll
            for (int jj = 0; jj < 8; ++jj)
                hi[jj] = (short)bf16_rne(fv[jj]);
            Ahi[kt] = hi;
        }

        floatx4 acc[4];
        #pragma unroll
        for (int nt = 0; nt < 4; ++nt) { acc[nt][0]=0.f; acc[nt][1]=0.f; acc[nt][2]=0.f; acc[nt][3]=0.f; }

        #pragma unroll
        for (int nt = 0; nt < 4; ++nt) {
            #pragma unroll
            for (int kt = 0; kt < 2; ++kt) {
                int fbase = ((p * 2 + kt) * 4 + nt) * 64 + lane;
                short8 bhi = Bf[fbase];
                acc[nt] = __builtin_amdgcn_mfma_f32_16x16x32_bf16(Ahi[kt], bhi, acc[nt], 0, 0, 0);
            }
        }
        // relu-write back (same-wave RAW ordered by in-order DS pipe)
        #pragma unroll
        for (int nt = 0; nt < 4; ++nt) {
            #pragma unroll
            for (int reg = 0; reg < 4; ++reg) {
                int row = w * 16 + quad * 4 + reg;
                H[row * HSTRIDE + nt * 16 + mrow] = fmaxf(acc[nt][reg], 0.f);
            }
        }
    }
    __syncthreads();   // the ONE cross-wave barrier: store+pool read all 32 rows

    // ---- store h as fp8 e5m2 for next layer (coalesced uchar4, guarded tail) ----
    #pragma unroll
    for (int i = 0; i < 4; ++i) {
        int t4 = tid + i * BLK;
        int r  = t4 >> 4;
        int c  = (t4 & 15) << 2;
        int grow = n0 + r;
        if (grow < N_NODES) {
            float4 v = *(const float4*)&H[r * HSTRIDE + c];
            uchar4 u;
            u.x = f32_e5m2(v.x); u.y = f32_e5m2(v.y);
            u.z = f32_e5m2(v.z); u.w = f32_e5m2(v.w);
            *(uchar4*)(h_out + (size_t)grow * DIM + c) = u;
        }
    }

    // ---- pool partial (fp32 H; invalid rows hold exact zeros) ----
    if (tid < 64) {
        float s = 0.f;
        #pragma unroll
        for (int r = 0; r < ROWS; ++r)
            s += H[r * HSTRIDE + tid];
        atomicAdd(&pooled[(blockIdx.x & (POOL_REP - 1)) * DIM + tid], s);
    }

    // ---- layer-5 only: last-finished block computes the output (no spinning, no barrier) ----
    if (doFinal) {
        __threadfence();   // release: my pooled atomicAdds precede my ticket increment
        if (tid == 0) {
            int tk = __hip_atomic_fetch_add(ticket, 1, __ATOMIC_ACQ_REL, __HIP_MEMORY_SCOPE_AGENT);
            winner = (tk == GRID_L - 1);   // acquire pairs with all other blocks' releases
        }
        __syncthreads();
        if (winner && tid < 64) {
            int c = tid;
            float s = 0.f;
            for (int l = 0; l < N_LAYERS; ++l) {
                float col = 0.f;
                for (int r = 0; r < POOL_REP; ++r)
                    col += __hip_atomic_load(&poolAll[(l * POOL_REP + r) * DIM + c],
                                             __ATOMIC_RELAXED, __HIP_MEMORY_SCOPE_AGENT);
                s += col * Wl[l * DIM + c];
            }
            #pragma unroll
            for (int off = 32; off > 0; off >>= 1)
                s += __shfl_down(s, off, 64);
            if (c == 0) {
                float logit = s / (float)N_NODES;
                out[0] = 1.f / (1.f + expf(-logit));
            }
        }
    }
}

extern "C" void kernel_launch(void* const* d_in, const int* in_sizes, int n_in,
                              void* d_out, int out_size, void* d_ws, size_t ws_size,
                              hipStream_t stream) {
    const float* x   = (const float*)d_in[0];
    const float* W   = (const float*)d_in[1];
    const float* Wl  = (const float*)d_in[2];
    const int*   src = (const int*)d_in[3];
    const int*   dst = (const int*)d_in[4];
    float* out = (float*)d_out;

    char* ws = (char*)d_ws;
    const size_t h8Bytes = (size_t)N_NODES * DIM;                     // 3.2 MB
    unsigned char* hX = (unsigned char*)(ws);
    unsigned char* hA = (unsigned char*)(ws + h8Bytes);
    unsigned char* hB = (unsigned char*)(ws + 2 * h8Bytes);
    unsigned short* ell = (unsigned short*)(ws + 3 * h8Bytes);        // 50176*64 ushort = 6.4 MB
    int*   ebuf     = (int*)(ell + (size_t)NROW_PAD * CAP);           // 196*5632*4 = 4.4 MB
    int*   rowCnt   = ebuf + (size_t)NB * CAPB;                       // 50176 ints
    int*   bucketCnt= rowCnt + NROW_PAD;                              // 256 ints (padded)
    int*   ticket   = bucketCnt + 256;                                // 64 ints (padded)
    float* pooled   = (float*)(ticket + 64);                          // 5*64*64 floats
    unsigned short* wfrag = (unsigned short*)(pooled + N_LAYERS * POOL_REP * DIM);

    // zero bucketCnt + ticket + pooled in one tiny stream-ordered memset (before any atomics)
    hipMemsetAsync(bucketCnt, 0, (256 + 64 + N_LAYERS * POOL_REP * DIM) * sizeof(int), stream);

    setup_kernel<<<PREP_BLOCKS + BF_BLOCKS, 256, 0, stream>>>(x, W, src, dst, hX, wfrag, bucketCnt, ebuf);
    bell_kernel<<<NB, 512, 0, stream>>>(ebuf, bucketCnt, rowCnt, ell);

    const unsigned char* hcur = hX;
    unsigned char* hnext = hA;
    for (int l = 0; l < N_LAYERS; ++l) {
        layer_kernel<<<GRID_L, BLK, 0, stream>>>(
            hcur, rowCnt, ell, wfrag + (size_t)l * WFRAG_PER_LAYER, hnext,
            pooled + (size_t)l * POOL_REP * DIM,
            (l == N_LAYERS - 1) ? 1 : 0, ticket, pooled, Wl, out);
        hcur = hnext;
        hnext = (hnext == hA) ? hB : hA;
    }
}

// Round 14
// 181.283 us; speedup vs baseline: 2.6689x; 1.5038x over previous
//
#include <hip/hip_runtime.h>
#include <hip/hip_fp16.h>
#include <math.h>

#define N_NODES 50000
#define N_EDGES 800000
#define DIM 64
#define N_LAYERS 5

#define BLK 128      // two waves per block (R9 measured-best)
#define ROWS 32      // 16 rows per wave
#define HSTRIDE 68   // 16B-aligned rows, bank-spread
#define POOL_REP 16

#define CAP 64       // ELL row capacity (deg ~ Poisson(16); P(>64) ~ 1e-13, guarded)
#define NB 196       // buckets of 256 dst rows
#define NROW_PAD (NB * 256)   // 50176
#define CAPB 5632    // per-bucket edge capacity (mean 4082, sigma ~64)
#define BF_BLOCKS 512
#define EPB2 ((N_EDGES + BF_BLOCKS - 1) / BF_BLOCKS)   // 1563 edges per fill chunk

#define WFRAG_PER_LAYER (3 * 2 * 4 * 64 * 8)   // 12288 shorts (hi-only)
#define XP (N_NODES * DIM / 4)                  // 800000 x-conv items
#define WP (N_LAYERS * WFRAG_PER_LAYER)         // 61440 w-conv items
#define PREP_BLOCKS ((XP + WP) / 256)           // 3365 exact

typedef __attribute__((ext_vector_type(8))) short short8;
typedef __attribute__((ext_vector_type(8))) unsigned short ushort8_t;
typedef __attribute__((ext_vector_type(4))) float floatx4;
typedef __attribute__((ext_vector_type(4))) unsigned uint4v;   // NT-store-compatible 16B vector

__device__ inline unsigned short bf16_rne(float f) {
    unsigned int u = __float_as_uint(f);
    return (unsigned short)((u + 0x7FFFu + ((u >> 16) & 1u)) >> 16);
}
// fp8 e5m2 = top byte of fp16. Decode: 2 ops. Encode: f32->f16 RNE, then RNE on 8-bit boundary.
__device__ inline float e5m2_f32(unsigned char b) {
    return __half2float(__ushort_as_half((unsigned short)((unsigned short)b << 8)));
}
__device__ inline unsigned char f32_e5m2(float f) {
    unsigned short us = __half_as_ushort(__float2half(f));
    us = (unsigned short)(us + 0x7F + ((us >> 8) & 1));
    return (unsigned char)(us >> 8);
}
// Pack bytes {b0,b1} / {b2,b3} of a dword into half2 {b<<8, b'<<8} via v_perm_b32.
__device__ inline __half2 e5m2x2_lo(unsigned d) {
    unsigned h = __builtin_amdgcn_perm(0u, d, 0x01050004u);  // bytes [0,b0,0,b1]
    return __builtin_bit_cast(__half2, h);
}
__device__ inline __half2 e5m2x2_hi(unsigned d) {
    unsigned h = __builtin_amdgcn_perm(0u, d, 0x03070206u);  // bytes [0,b2,0,b3]
    return __builtin_bit_cast(__half2, h);
}

// ---------------- merged setup (R6-proven): prep (x->fp8, W->frags) + bucketed edge partition ----
// bucketCnt zeroed by hipMemsetAsync BEFORE this kernel (stream-ordered).
__global__ __launch_bounds__(256) void setup_kernel(const float* __restrict__ x,
                                                    const float* __restrict__ W,
                                                    const int* __restrict__ src,
                                                    const int* __restrict__ dst,
                                                    unsigned char* __restrict__ x8,
                                                    unsigned short* __restrict__ wfrag,
                                                    int* __restrict__ bucketCnt,
                                                    int* __restrict__ ebuf) {
    __shared__ int cnt[NB];
    __shared__ int basev[NB];
    int b = blockIdx.x;
    const int t = threadIdx.x;
    if (b < PREP_BLOCKS) {
        int i = b * 256 + t;
        if (i < XP) {
            float4 v = ((const float4*)x)[i];
            uchar4 u;
            u.x = f32_e5m2(v.x); u.y = f32_e5m2(v.y);
            u.z = f32_e5m2(v.z); u.w = f32_e5m2(v.w);
            // NT store: leave h0 clean in L3, not dirty in this XCD's L2 (cross-XCD read fix)
            __builtin_nontemporal_store(__builtin_bit_cast(unsigned, u), (unsigned*)x8 + i);
        } else {
            int tt = i - XP;   // < WP exactly
            int j    = tt & 7;
            int lane = (tt >> 3) & 63;
            int nt   = (tt >> 9) & 3;
            int kt   = (tt >> 11) & 1;
            int rest = tt >> 12;
            int p    = rest % 3;
            int layer= rest / 3;
            int k = kt * 32 + (lane >> 4) * 8 + j;
            int n = nt * 16 + (lane & 15);
            float v = W[(((size_t)layer * 3 + p) * 64 + k) * 64 + n];
            wfrag[tt] = bf16_rne(v);
        }
        return;
    }
    // ---- bfill part: bucketed partition of one edge chunk (LDS atomics only) ----
    b -= PREP_BLOCKS;
    const int e0 = b * EPB2;
    for (int j = t; j < NB; j += 256) cnt[j] = 0;
    __syncthreads();
    for (int i = t; i < EPB2; i += 256) {
        int e = e0 + i;
        if (e < N_EDGES) atomicAdd(&cnt[dst[e] >> 8], 1);
    }
    __syncthreads();
    for (int j = t; j < NB; j += 256) {
        int c = cnt[j];
        basev[j] = c ? atomicAdd(&bucketCnt[j], c) : 0;
        cnt[j] = 0;   // reuse as in-block cursor
    }
    __syncthreads();
    for (int i = t; i < EPB2; i += 256) {
        int e = e0 + i;
        if (e < N_EDGES) {
            int d = dst[e];
            int bb = d >> 8;
            int pos = atomicAdd(&cnt[bb], 1);
            ebuf[(size_t)bb * CAPB + basev[bb] + pos] = ((d & 255) << 16) | src[e];
        }
    }
}

// ---------------- bucket -> ELL: LDS scatter tile, coalesced NT uint4 writeout ----------------
__global__ __launch_bounds__(512) void bell_kernel(const int* __restrict__ ebuf,
                                                   const int* __restrict__ bucketCnt,
                                                   int* __restrict__ rowCnt,
                                                   unsigned short* __restrict__ ell) {
    __shared__ int cur[256];
    __shared__ unsigned short tile[256 * CAP];   // 32 KB
    const int t = threadIdx.x;       // 0..511
    const int b = blockIdx.x;
    const int cnt_b = min(bucketCnt[b], CAPB);
    const int* __restrict__ ereg = ebuf + (size_t)b * CAPB;

    if (t < 256) cur[t] = 0;
    __syncthreads();
    for (int i = t; i < cnt_b; i += 512) {
        int e = ereg[i];
        int r = (e >> 16) & 255;
        int pos = atomicAdd(&cur[r], 1);
        if (pos < CAP)                        // overflow guard: degrade, don't corrupt
            tile[r * CAP + pos] = (unsigned short)(e & 0xFFFF);
    }
    __syncthreads();
    if (t < 256) rowCnt[b * 256 + t] = min(cur[t], CAP);
    // NT writeout: ell lands clean in L3, readable by all XCDs without dirty snoops
    uint4v* eo = (uint4v*)(ell + (size_t)b * 256 * CAP);
    const uint4v* ti = (const uint4v*)tile;
    #pragma unroll
    for (int j = 0; j < 4; ++j)
        __builtin_nontemporal_store(ti[t + j * 512], eo + t + j * 512);
}

// ---------------- fused layer (R9 ELL gather, measured-best; NT h_out stores) ----------------
__global__ __launch_bounds__(BLK) void layer_kernel(const unsigned char* __restrict__ h8,
                                                    const int* __restrict__ rowCnt,
                                                    const unsigned short* __restrict__ ell,
                                                    const unsigned short* __restrict__ wf,
                                                    unsigned char* __restrict__ h_out,
                                                    float* __restrict__ pooled) {  // [POOL_REP][64]
    __shared__ float H[ROWS * HSTRIDE];   // 8.7 KB
    const int tid  = threadIdx.x;
    const int lane = tid & 63;
    const int w    = __builtin_amdgcn_readfirstlane(tid >> 6);
    const int n0   = blockIdx.x * ROWS;
    const int nw   = n0 + w * 16;
    const int o8   = (lane & 7) << 3;     // byte offset of this lane's 8 dims
    const int rg   = lane >> 3;           // row id 0..7 within octet-group

    const int cv = rowCnt[nw + (lane & 15)];   // per-row degree (16 rows, broadcast x4)

    // 2 groups of 8 rows; octet rg owns row 8g+rg; lane holds 8 dims at byte offset o8
    for (int g = 0; g < 2; ++g) {
        const int myrow = g * 8 + rg;
        const int deg = min(__shfl(cv, myrow, 64), CAP);
        int Rm = deg;
        Rm = max(Rm, __shfl_xor(Rm, 8, 64));
        Rm = max(Rm, __shfl_xor(Rm, 16, 64));
        Rm = max(Rm, __shfl_xor(Rm, 32, 64));   // max over the 8 rows -> wave-uniform
        const int Rpad = (Rm + 7) & ~7;
        const int rowq = nw + myrow;
        const int rq6  = rowq << 6;
        const unsigned short* ep = ell + ((size_t)rowq << 6);  // CAP=64 stride

        __half2 a01 = __float2half2_rn(0.f);
        __half2 a23 = a01, a45 = a01, a67 = a01;

        for (int i = 0; i < Rpad; i += 8) {
            ushort8_t ev = *(const ushort8_t*)(ep + i);   // 8 edge ids, broadcast across 8 lanes
            uint2 dv[8];
            #pragma unroll
            for (int k = 0; k < 8; ++k) {
                int s6 = ((int)ev[k]) << 6;
                s6 = (i + k < deg) ? s6 : rq6;            // pad slots -> self (cancelled below)
                dv[k] = *(const uint2*)(h8 + (unsigned)(s6 | o8));
            }
            #pragma unroll
            for (int k = 0; k < 8; ++k) {
                a01 = __hadd2(a01, e5m2x2_lo(dv[k].x));
                a23 = __hadd2(a23, e5m2x2_hi(dv[k].x));
                a45 = __hadd2(a45, e5m2x2_lo(dv[k].y));
                a67 = __hadd2(a67, e5m2x2_hi(dv[k].y));
            }
        }

        // self + exact pad-cancellation (pads added self Rpad-deg times)
        uint2 sd = *(const uint2*)(h8 + (unsigned)(rq6 | o8));
        float scale = (float)(1 - (Rpad - deg));
        float2 f01 = __half22float2(a01), f23 = __half22float2(a23);
        float2 f45 = __half22float2(a45), f67 = __half22float2(a67);
        float4 r0, r1;
        r0.x = f01.x + e5m2_f32((unsigned char)(sd.x      )) * scale;
        r0.y = f01.y + e5m2_f32((unsigned char)(sd.x >>  8)) * scale;
        r0.z = f23.x + e5m2_f32((unsigned char)(sd.x >> 16)) * scale;
        r0.w = f23.y + e5m2_f32((unsigned char)(sd.x >> 24)) * scale;
        r1.x = f45.x + e5m2_f32((unsigned char)(sd.y      )) * scale;
        r1.y = f45.y + e5m2_f32((unsigned char)(sd.y >>  8)) * scale;
        r1.z = f67.x + e5m2_f32((unsigned char)(sd.y >> 16)) * scale;
        r1.w = f67.y + e5m2_f32((unsigned char)(sd.y >> 24)) * scale;
        if (rowq >= N_NODES) {
            r0.x = 0.f; r0.y = 0.f; r0.z = 0.f; r0.w = 0.f;
            r1.x = 0.f; r1.y = 0.f; r1.z = 0.f; r1.w = 0.f;
        }
        float* hp = &H[(w * 16 + myrow) * HSTRIDE + o8];
        *(float4*)hp = r0;
        *(float4*)(hp + 4) = r1;
    }
    // no __syncthreads: aggregation, MFMA A/outputs, relu writes all stay within
    // this wave's 16 H rows; per-wave DS-pipe ordering guarantees RAW/WAR.
    asm volatile("s_waitcnt lgkmcnt(0)" ::: "memory");

    // ---- MLP: hi-only bf16 MFMA (wave-private in H; zero inter-stage barriers) ----
    const int mrow = lane & 15;
    const int quad = lane >> 4;
    const short8* Bf = (const short8*)wf;

    for (int p = 0; p < 3; ++p) {
        short8 Ahi[2];
        #pragma unroll
        for (int kt = 0; kt < 2; ++kt) {
            const float* ap = &H[(w * 16 + mrow) * HSTRIDE + kt * 32 + quad * 8];
            float4 f0 = *(const float4*)ap;
            float4 f1 = *(const float4*)(ap + 4);
            float fv[8] = {f0.x, f0.y, f0.z, f0.w, f1.x, f1.y, f1.z, f1.w};
            short8 hi;
            #pragma unroll
            for (int jj = 0; jj < 8; ++jj)
                hi[jj] = (short)bf16_rne(fv[jj]);
            Ahi[kt] = hi;
        }

        floatx4 acc[4];
        #pragma unroll
        for (int nt = 0; nt < 4; ++nt) { acc[nt][0]=0.f; acc[nt][1]=0.f; acc[nt][2]=0.f; acc[nt][3]=0.f; }

        #pragma unroll
        for (int nt = 0; nt < 4; ++nt) {
            #pragma unroll
            for (int kt = 0; kt < 2; ++kt) {
                int fbase = ((p * 2 + kt) * 4 + nt) * 64 + lane;
                short8 bhi = Bf[fbase];
                acc[nt] = __builtin_amdgcn_mfma_f32_16x16x32_bf16(Ahi[kt], bhi, acc[nt], 0, 0, 0);
            }
        }
        // relu-write back (same-wave RAW ordered by in-order DS pipe)
        #pragma unroll
        for (int nt = 0; nt < 4; ++nt) {
            #pragma unroll
            for (int reg = 0; reg < 4; ++reg) {
                int row = w * 16 + quad * 4 + reg;
                H[row * HSTRIDE + nt * 16 + mrow] = fmaxf(acc[nt][reg], 0.f);
            }
        }
    }
    __syncthreads();   // the ONE cross-wave barrier: store+pool read all 32 rows

    // ---- store h as fp8 e5m2: NON-TEMPORAL -> clean L3, no dirty cross-XCD snoops next layer ----
    #pragma unroll
    for (int i = 0; i < 4; ++i) {
        int t4 = tid + i * BLK;
        int r  = t4 >> 4;
        int c  = (t4 & 15) << 2;
        int grow = n0 + r;
        if (grow < N_NODES) {
            float4 v = *(const float4*)&H[r * HSTRIDE + c];
            uchar4 u;
            u.x = f32_e5m2(v.x); u.y = f32_e5m2(v.y);
            u.z = f32_e5m2(v.z); u.w = f32_e5m2(v.w);
            __builtin_nontemporal_store(__builtin_bit_cast(unsigned, u),
                                        (unsigned*)(h_out + (size_t)grow * DIM + c));
        }
    }

    // ---- pool partial (fp32 H; invalid rows hold exact zeros) ----
    if (tid < 64) {
        float s = 0.f;
        #pragma unroll
        for (int r = 0; r < ROWS; ++r)
            s += H[r * HSTRIDE + tid];
        atomicAdd(&pooled[(blockIdx.x & (POOL_REP - 1)) * DIM + tid], s);
    }
}

__global__ void finalize_kernel(const float* __restrict__ pooled,  // [L][POOL_REP][64]
                                const float* __restrict__ Wl,
                                float* __restrict__ out) {
    int c = threadIdx.x;  // 64
    float s = 0.f;
    #pragma unroll
    for (int l = 0; l < N_LAYERS; ++l) {
        float col = 0.f;
        #pragma unroll
        for (int r = 0; r < POOL_REP; ++r)
            col += pooled[(l * POOL_REP + r) * DIM + c];
        s += col * Wl[l * DIM + c];
    }
    #pragma unroll
    for (int off = 32; off > 0; off >>= 1)
        s += __shfl_down(s, off, 64);
    if (c == 0) {
        float logit = s / (float)N_NODES;
        out[0] = 1.f / (1.f + expf(-logit));
    }
}

extern "C" void kernel_launch(void* const* d_in, const int* in_sizes, int n_in,
                              void* d_out, int out_size, void* d_ws, size_t ws_size,
                              hipStream_t stream) {
    const float* x   = (const float*)d_in[0];
    const float* W   = (const float*)d_in[1];
    const float* Wl  = (const float*)d_in[2];
    const int*   src = (const int*)d_in[3];
    const int*   dst = (const int*)d_in[4];
    float* out = (float*)d_out;

    char* ws = (char*)d_ws;
    const size_t h8Bytes = (size_t)N_NODES * DIM;                     // 3.2 MB
    unsigned char* hX = (unsigned char*)(ws);
    unsigned char* hA = (unsigned char*)(ws + h8Bytes);
    unsigned char* hB = (unsigned char*)(ws + 2 * h8Bytes);
    unsigned short* ell = (unsigned short*)(ws + 3 * h8Bytes);        // 50176*64 ushort = 6.4 MB
    int*   ebuf     = (int*)(ell + (size_t)NROW_PAD * CAP);           // 196*5632*4 = 4.4 MB
    int*   rowCnt   = ebuf + (size_t)NB * CAPB;                       // 50176 ints
    int*   bucketCnt= rowCnt + NROW_PAD;                              // 256 ints (padded)
    float* pooled   = (float*)(bucketCnt + 256);                      // 5*16*64 floats
    unsigned short* wfrag = (unsigned short*)(pooled + N_LAYERS * POOL_REP * DIM);

    // zero bucketCnt + pooled in one tiny stream-ordered memset (before any atomics)
    hipMemsetAsync(bucketCnt, 0, (256 + N_LAYERS * POOL_REP * DIM) * sizeof(int), stream);

    setup_kernel<<<PREP_BLOCKS + BF_BLOCKS, 256, 0, stream>>>(x, W, src, dst, hX, wfrag, bucketCnt, ebuf);
    bell_kernel<<<NB, 512, 0, stream>>>(ebuf, bucketCnt, rowCnt, ell);

    const unsigned char* hcur = hX;
    unsigned char* hnext = hA;
    const int grid = (N_NODES + ROWS - 1) / ROWS;   // 1563
    for (int l = 0; l < N_LAYERS; ++l) {
        layer_kernel<<<grid, BLK, 0, stream>>>(
            hcur, rowCnt, ell, wfrag + (size_t)l * WFRAG_PER_LAYER, hnext,
            pooled + (size_t)l * POOL_REP * DIM);
        hcur = hnext;
        hnext = (hnext == hA) ? hB : hA;
    }
    finalize_kernel<<<1, 64, 0, stream>>>(pooled, Wl, out);
}